// Round 5
// baseline (574.405 us; speedup 1.0000x reference)
//
#include <hip/hip_runtime.h>
#include <hip/hip_bf16.h>

#define N_TOK 4096
#define D_MODEL 2048
#define NHEAD 16
#define DKH 128

typedef __attribute__((ext_vector_type(8))) short short8v;
typedef __attribute__((ext_vector_type(4))) float f32x4;
typedef __attribute__((ext_vector_type(8))) unsigned short ush8;

static __device__ __forceinline__ unsigned short f2bf(float f) {
  unsigned int x = __float_as_uint(f);
  return (unsigned short)((x + 0x7fffu + ((x >> 16) & 1u)) >> 16);
}
static __device__ __forceinline__ float bf2f(unsigned short u) {
  return __uint_as_float(((unsigned int)u) << 16);
}

// async global->LDS, 16B per lane (attn only)
static __device__ __forceinline__ void gld16(const void* g, void* l) {
  __builtin_amdgcn_global_load_lds(
      (const __attribute__((address_space(1))) unsigned int*)g,
      (__attribute__((address_space(3))) unsigned int*)l, 16, 0, 0);
}

// ---------------- Fragment-linear layouts (proj reads NO LDS) ------------------
// A 16x32 bf16 MFMA fragment tile = 64 lanes x 8 elems, stored lane-linear:
//   block(nb_or_mh, kidx, tile): elems [lane(64)][8], lane = fq*16+fr
//   addr = ((base64*64 + kidx)*8 + tile)*512 + lane*8      (elements)
// E: base64 = nb (128-token block), tile = token/16 within block, kidx = d/32.
// W: base64 = mat*16+h,            tile = dk/16,             kidx = d/32.

// ---------------- Split kernels (memory-bound, run once) -----------------------
__global__ __launch_bounds__(256)
void split_e_kernel(const float* __restrict__ E,
                    unsigned short* __restrict__ Eh,
                    unsigned short* __restrict__ El) {
  const size_t i = ((size_t)blockIdx.x * 256 + threadIdx.x) * 8;
  const int n = (int)(i >> 11), d0 = (int)(i & 2047);
  float4 v0 = *reinterpret_cast<const float4*>(E + i);
  float4 v1 = *reinterpret_cast<const float4*>(E + i + 4);
  float f[8] = {v0.x, v0.y, v0.z, v0.w, v1.x, v1.y, v1.z, v1.w};
  ush8 hi, lo;
#pragma unroll
  for (int j = 0; j < 8; ++j) {
    unsigned short hu = f2bf(f[j]);
    hi[j] = hu;
    lo[j] = f2bf(f[j] - bf2f(hu));
  }
  const int nb = n >> 7, mt = (n >> 4) & 7, fr = n & 15;
  const int kidx = d0 >> 5, fq = (d0 >> 3) & 3;
  const size_t off = ((((size_t)nb * 64 + kidx) * 8 + mt) * 64 + fq * 16 + fr) * 8;
  *reinterpret_cast<ush8*>(Eh + off) = hi;
  *reinterpret_cast<ush8*>(El + off) = lo;
}

// W[h][d][k] -> frag-linear WB (hi for Q,K,V; lo for Q,K). Q scale folded here.
__global__ __launch_bounds__(256)
void split_w_kernel(const float* __restrict__ Wq, const float* __restrict__ Wk,
                    const float* __restrict__ Wv,
                    unsigned short* __restrict__ WBh,
                    unsigned short* __restrict__ WBl) {
  __shared__ float tile[64][65];
  const int t = threadIdx.x;
  const int d0 = blockIdx.x * 64;
  const int k0 = blockIdx.y * 64;
  const int mh = blockIdx.z;
  const int mat = mh >> 4, h = mh & 15;
  const float* W = (mat == 0) ? Wq : (mat == 1) ? Wk : Wv;
  const float* Wp = W + (size_t)h * D_MODEL * DKH;
  const float fac = (mat == 0) ? (1.44269504089f / sqrtf(128.0f)) : 1.0f;

  const int rr = t >> 4, c4 = (t & 15) * 4;
#pragma unroll
  for (int p = 0; p < 4; ++p) {
    float4 v = *reinterpret_cast<const float4*>(Wp + (size_t)(d0 + rr + 16 * p) * DKH + k0 + c4);
    tile[rr + 16 * p][c4 + 0] = v.x * fac;
    tile[rr + 16 * p][c4 + 1] = v.y * fac;
    tile[rr + 16 * p][c4 + 2] = v.z * fac;
    tile[rr + 16 * p][c4 + 3] = v.w * fac;
  }
  __syncthreads();
  const int dd0 = (t & 7) * 8, kl = t >> 3;
  const int kidx = ((d0 + dd0) >> 5), fq = (dd0 >> 3) & 3;
#pragma unroll
  for (int p = 0; p < 2; ++p) {
    const int kg = k0 + kl + 32 * p;
    const int nt = kg >> 4, fr = kg & 15;
    ush8 hi, lo;
#pragma unroll
    for (int j = 0; j < 8; ++j) {
      float f = tile[dd0 + j][kl + 32 * p];
      unsigned short hu = f2bf(f);
      hi[j] = hu;
      lo[j] = f2bf(f - bf2f(hu));
    }
    const size_t dst = ((((size_t)mh * 64 + kidx) * 8 + nt) * 64 + fq * 16 + fr) * 8;
    *reinterpret_cast<ush8*>(WBh + dst) = hi;
    if (mat < 2) *reinterpret_cast<ush8*>(WBl + dst) = lo;
  }
}

// ---------------- Projection GEMM v2: no LDS, all-direct frag loads ------------
// MODE 0: Q/K, 3-term emulated bf16.  MODE 1: V, 1-term, output transposed.
template <int MODE>
__global__ __launch_bounds__(256)
void proj2_kernel(const unsigned short* __restrict__ EhF,
                  const unsigned short* __restrict__ ElF,
                  const unsigned short* __restrict__ WBh,
                  const unsigned short* __restrict__ WBl,
                  unsigned short* __restrict__ Qhi, unsigned short* __restrict__ Qlo,
                  unsigned short* __restrict__ Khi, unsigned short* __restrict__ Klo,
                  unsigned short* __restrict__ Vt, int h0, int HC) {
  // XCD swizzle -> contiguous logical chunk per XCD (nb-major grid => E reuse in L2)
  int id = blockIdx.x;
  const int nwg = gridDim.x;
  id = (id & 7) * (nwg >> 3) + (id >> 3);
  int nb, hl, mat;
  if (MODE == 0) {
    const int hm2 = id % (2 * HC);
    nb = id / (2 * HC);
    mat = hm2 & 1;
    hl = hm2 >> 1;
  } else {
    nb = id / HC;
    hl = id % HC;
    mat = 2;
  }
  const int h = h0 + hl;
  const int t = threadIdx.x;
  const int wv = t >> 6, lane = t & 63, fr = lane & 15, fq = lane >> 4;
  const int m0 = (wv >> 1) * 64, n0 = (wv & 1) * 64;

  constexpr int NF = (MODE == 0) ? 8 : 4;
  const unsigned short *Ab, *Al = nullptr, *Bb, *Bl = nullptr;
  if (MODE == 0) {
    Ab = EhF + (size_t)nb * 64 * 4096 + lane * 8;
    Al = ElF + (size_t)nb * 64 * 4096 + lane * 8;
    const size_t wb = (size_t)(mat * NHEAD + h) * 64 * 4096;
    Bb = WBh + wb + lane * 8;
    Bl = WBl + wb + lane * 8;
  } else {
    Ab = WBh + (size_t)(2 * NHEAD + h) * 64 * 4096 + lane * 8;
    Bb = EhF + (size_t)nb * 64 * 4096 + lane * 8;
  }
  const int ta = m0 >> 4, tb = n0 >> 4;

  f32x4 acc[4][4];
#pragma unroll
  for (int a = 0; a < 4; ++a)
#pragma unroll
    for (int b = 0; b < 4; ++b) acc[a][b] = f32x4{0.f, 0.f, 0.f, 0.f};

  auto loadf = [&](short8v* A, short8v* B, int kidx) {
    const size_t ko = (size_t)kidx * 4096;
#pragma unroll
    for (int i = 0; i < 4; ++i) {
      A[i] = *reinterpret_cast<const short8v*>(Ab + ko + (ta + i) * 512);
      B[i] = *reinterpret_cast<const short8v*>(Bb + ko + (tb + i) * 512);
      if (MODE == 0) {
        A[4 + i] = *reinterpret_cast<const short8v*>(Al + ko + (ta + i) * 512);
        B[4 + i] = *reinterpret_cast<const short8v*>(Bl + ko + (tb + i) * 512);
      }
    }
  };
  auto mfmas = [&](const short8v* A, const short8v* B) {
#pragma unroll
    for (int ni = 0; ni < 4; ++ni)
#pragma unroll
      for (int mi = 0; mi < 4; ++mi) {
        acc[mi][ni] = __builtin_amdgcn_mfma_f32_16x16x32_bf16(A[mi], B[ni], acc[mi][ni], 0, 0, 0);
        if (MODE == 0) {
          acc[mi][ni] = __builtin_amdgcn_mfma_f32_16x16x32_bf16(A[mi], B[4 + ni], acc[mi][ni], 0, 0, 0);
          acc[mi][ni] = __builtin_amdgcn_mfma_f32_16x16x32_bf16(A[4 + mi], B[ni], acc[mi][ni], 0, 0, 0);
        }
      }
  };

  short8v aP[NF], bP[NF], aQ[NF], bQ[NF];   // 2-deep static ping-pong (rule #20)
  loadf(aP, bP, 0);
  for (int k2 = 0; k2 < 64; k2 += 2) {
    loadf(aQ, bQ, k2 + 1);
    mfmas(aP, bP);
    if (k2 + 2 < 64) loadf(aP, bP, k2 + 2);
    mfmas(aQ, bQ);
  }

  if (MODE == 0) {
    unsigned short* Ohi = (mat == 0) ? Qhi : Khi;
    unsigned short* Olo = (mat == 0) ? Qlo : Klo;
#pragma unroll
    for (int mi = 0; mi < 4; ++mi)
#pragma unroll
      for (int ni = 0; ni < 4; ++ni)
#pragma unroll
        for (int i = 0; i < 4; ++i) {
          float v = acc[mi][ni][i];
          unsigned short hu = f2bf(v);
          unsigned short lu = f2bf(v - bf2f(hu));
          int n = nb * 128 + m0 + 16 * mi + fq * 4 + i;   // C: row=(lane>>4)*4+i
          int k = n0 + 16 * ni + fr;                      //    col=lane&15
          if (mat == 1) k ^= ((n & 7) << 3);              // attn K-LDS inverse swizzle
          size_t off = ((size_t)hl * N_TOK + n) * DKH + k;
          Ohi[off] = hu;
          Olo[off] = lu;
        }
  } else {
#pragma unroll
    for (int mi = 0; mi < 4; ++mi)
#pragma unroll
      for (int ni = 0; ni < 4; ++ni)
#pragma unroll
        for (int i = 0; i < 4; ++i) {
          int kout = m0 + 16 * mi + fq * 4 + i;
          int tn = nb * 128 + n0 + 16 * ni + fr;
          int ts = (tn & ~63) | ((tn & 63) ^ ((kout & 7) << 3));  // attn V swizzle
          Vt[((size_t)hl * DKH + kout) * N_TOK + ts] = f2bf(acc[mi][ni][i]);
        }
  }
}

// ---------------- Flash attention (unchanged from round 4) ---------------------
__global__ __launch_bounds__(256, 2)
void attn_kernel(const unsigned short* __restrict__ Qhi,
                 const unsigned short* __restrict__ Qlo,
                 const unsigned short* __restrict__ Khi,
                 const unsigned short* __restrict__ Klo,
                 const unsigned short* __restrict__ Vt,
                 float* __restrict__ out, int h0, int HC)
{
  __shared__ alignas(16) unsigned short KhiL[64][128];
  __shared__ alignas(16) unsigned short KloL[64][128];
  __shared__ alignas(16) unsigned short VtL[128][64];
  __shared__ unsigned int PL32[4][2][32][20];

  const int t = threadIdx.x;
  int b = blockIdx.x;
  const int nwg = 32 * HC;
  if ((nwg & 7) == 0) b = (b & 7) * (nwg >> 3) + (b >> 3);
  const int qb = b & 31;
  const int hl = b >> 5;
  const int h  = h0 + hl;
  const int wv = t >> 6, lane = t & 63;
  const int fr = lane & 15, fq = lane >> 4;
  const int q0 = qb * 128 + wv * 32;

  short8v qhi[2][4], qlo[2][4];
#pragma unroll
  for (int m = 0; m < 2; ++m) {
    const unsigned short* qp  = Qhi + ((size_t)hl * N_TOK + q0 + m * 16 + fr) * DKH + fq * 8;
    const unsigned short* qp2 = Qlo + ((size_t)hl * N_TOK + q0 + m * 16 + fr) * DKH + fq * 8;
#pragma unroll
    for (int kc = 0; kc < 4; ++kc) {
      qhi[m][kc] = *reinterpret_cast<const short8v*>(qp + kc * 32);
      qlo[m][kc] = *reinterpret_cast<const short8v*>(qp2 + kc * 32);
    }
  }

  f32x4 o[2][8];
#pragma unroll
  for (int m = 0; m < 2; ++m)
#pragma unroll
    for (int i = 0; i < 8; ++i) o[m][i] = f32x4{0.f, 0.f, 0.f, 0.f};
  float mrow[2] = {-__builtin_inff(), -__builtin_inff()};
  float lrow[2] = {0.f, 0.f};

  const char* KhiB = (const char*)(Khi + (size_t)hl * N_TOK * DKH);
  const char* KloB = (const char*)(Klo + (size_t)hl * N_TOK * DKH);
  const char* VtB  = (const char*)(Vt  + (size_t)hl * DKH * N_TOK);
  const int toff = t * 16;
  const int vrow = t >> 3, vbyte = (t & 7) * 16;

  for (int kt = 0; kt < N_TOK / 64; ++kt) {
    const int key0 = kt * 64;
    __syncthreads();
    {
      const char* gk  = KhiB + (size_t)key0 * 256;
      const char* gk2 = KloB + (size_t)key0 * 256;
#pragma unroll
      for (int j = 0; j < 4; ++j)
        gld16(gk + j * 4096 + toff, (char*)&KhiL[0][0] + j * 4096 + toff);
#pragma unroll
      for (int j = 0; j < 4; ++j)
        gld16(gk2 + j * 4096 + toff, (char*)&KloL[0][0] + j * 4096 + toff);
#pragma unroll
      for (int j = 0; j < 4; ++j)
        gld16(VtB + (size_t)(j * 32 + vrow) * (N_TOK * 2) + key0 * 2 + vbyte,
              (char*)&VtL[0][0] + j * 4096 + toff);
    }
    __syncthreads();

    f32x4 tt[2][4];
#pragma unroll
    for (int m = 0; m < 2; ++m)
#pragma unroll
      for (int kf = 0; kf < 4; ++kf) tt[m][kf] = f32x4{0.f, 0.f, 0.f, 0.f};
    __builtin_amdgcn_s_setprio(1);
#pragma unroll
    for (int kc = 0; kc < 4; ++kc) {
      short8v khf[4], klf[4];
#pragma unroll
      for (int kf = 0; kf < 4; ++kf) {
        const int kr = kf * 16 + fr;
        const int off = (kc * 32 + fq * 8) ^ ((kr & 7) << 3);
        khf[kf] = *reinterpret_cast<const short8v*>(&KhiL[kr][off]);
        klf[kf] = *reinterpret_cast<const short8v*>(&KloL[kr][off]);
      }
#pragma unroll
      for (int kf = 0; kf < 4; ++kf)
#pragma unroll
        for (int m = 0; m < 2; ++m) {
          tt[m][kf] = __builtin_amdgcn_mfma_f32_16x16x32_bf16(khf[kf], qhi[m][kc], tt[m][kf], 0, 0, 0);
          tt[m][kf] = __builtin_amdgcn_mfma_f32_16x16x32_bf16(klf[kf], qhi[m][kc], tt[m][kf], 0, 0, 0);
          tt[m][kf] = __builtin_amdgcn_mfma_f32_16x16x32_bf16(khf[kf], qlo[m][kc], tt[m][kf], 0, 0, 0);
        }
    }
    __builtin_amdgcn_s_setprio(0);

    float mx[2];
#pragma unroll
    for (int m = 0; m < 2; ++m) {
      float v = -__builtin_inff();
#pragma unroll
      for (int kf = 0; kf < 4; ++kf)
#pragma unroll
        for (int i = 0; i < 4; ++i) v = fmaxf(v, tt[m][kf][i]);
      v = fmaxf(v, __shfl_xor(v, 16));
      v = fmaxf(v, __shfl_xor(v, 32));
      mx[m] = v;
    }
    if (__any((mx[0] > mrow[0]) | (mx[1] > mrow[1]))) {
#pragma unroll
      for (int m = 0; m < 2; ++m) {
        float mn = fmaxf(mrow[m], mx[m]);
        float al = exp2f(mrow[m] - mn);
        mrow[m] = mn;
        lrow[m] *= al;
#pragma unroll
        for (int of = 0; of < 8; ++of)
#pragma unroll
          for (int i = 0; i < 4; ++i) o[m][of][i] *= al;
      }
    }
#pragma unroll
    for (int m = 0; m < 2; ++m) {
      float rs = 0.f;
#pragma unroll
      for (int kf = 0; kf < 4; ++kf)
#pragma unroll
        for (int hh = 0; hh < 2; ++hh) {
          float p0 = exp2f(tt[m][kf][2 * hh]     - mrow[m]);
          float p1 = exp2f(tt[m][kf][2 * hh + 1] - mrow[m]);
          unsigned short b0 = f2bf(p0), b1 = f2bf(p1);
          rs += bf2f(b0) + bf2f(b1);
          PL32[wv][m][kf * 8 + 2 * fq + hh][fr] = (unsigned)b0 | ((unsigned)b1 << 16);
        }
      rs += __shfl_xor(rs, 16);
      rs += __shfl_xor(rs, 32);
      lrow[m] += rs;
    }
    asm volatile("s_waitcnt lgkmcnt(0)" ::: "memory");
    __builtin_amdgcn_sched_barrier(0);

    __builtin_amdgcn_s_setprio(1);
#pragma unroll
    for (int ks = 0; ks < 2; ++ks) {
      union { unsigned u[4]; short8v v; } pb[2];
#pragma unroll
      for (int m = 0; m < 2; ++m)
#pragma unroll
        for (int w = 0; w < 4; ++w)
          pb[m].u[w] = PL32[wv][m][16 * ks + 4 * fq + w][fr];
#pragma unroll
      for (int of = 0; of < 8; ++of) {
        const int dr = of * 16 + fr;
        short8v av = *reinterpret_cast<const short8v*>(
            &VtL[dr][(ks * 32 + fq * 8) ^ ((dr & 7) << 3)]);
#pragma unroll
        for (int m = 0; m < 2; ++m)
          o[m][of] = __builtin_amdgcn_mfma_f32_16x16x32_bf16(av, pb[m].v, o[m][of], 0, 0, 0);
      }
    }
    __builtin_amdgcn_s_setprio(0);
  }

#pragma unroll
  for (int m = 0; m < 2; ++m) {
    float inv = 1.0f / lrow[m];
    int n = q0 + m * 16 + fr;
    float* op = out + (size_t)n * (NHEAD * DKH) + h * DKH + fq * 4;
#pragma unroll
    for (int of = 0; of < 8; ++of) {
      float4 r = make_float4(o[m][of][0] * inv, o[m][of][1] * inv,
                             o[m][of][2] * inv, o[m][of][3] * inv);
      *reinterpret_cast<float4*>(op + of * 16) = r;
    }
  }
}

// ---------------- host launch --------------------------------------------------
extern "C" void kernel_launch(void* const* d_in, const int* in_sizes, int n_in,
                              void* d_out, int out_size, void* d_ws, size_t ws_size,
                              hipStream_t stream) {
  (void)in_sizes; (void)n_in; (void)out_size;
  const float* E  = (const float*)d_in[0];
  const float* Wq = (const float*)d_in[1];
  const float* Wk = (const float*)d_in[2];
  const float* Wv = (const float*)d_in[3];
  float* out = (float*)d_out;

  const size_t ND   = (size_t)N_TOK * D_MODEL;           // 8388608
  const size_t WThE = (size_t)3 * NHEAD * DKH * D_MODEL; // 12582912
  const size_t WTlE = (size_t)2 * NHEAD * DKH * D_MODEL; // 8388608
  const size_t phe  = (size_t)N_TOK * DKH;               // 524288
  const size_t baseE = 2 * ND + WThE + WTlE;

  unsigned short* Eh  = (unsigned short*)d_ws;
  unsigned short* El  = Eh + ND;
  unsigned short* WBh = El + ND;
  unsigned short* WBl = WBh + WThE;
  unsigned short* chunk = WBl + WTlE;

  int HC = NHEAD;
  while (HC > 1 && (baseE + (size_t)HC * 5 * phe) * 2 > ws_size) HC >>= 1;

  split_e_kernel<<<dim3((unsigned)(ND / 8 / 256)), 256, 0, stream>>>(E, Eh, El);
  split_w_kernel<<<dim3(32, 2, 48), 256, 0, stream>>>(Wq, Wk, Wv, WBh, WBl);

  for (int h0 = 0; h0 < NHEAD; h0 += HC) {
    unsigned short* Qhi = chunk;
    unsigned short* Qlo = Qhi + (size_t)HC * phe;
    unsigned short* Khi = Qlo + (size_t)HC * phe;
    unsigned short* Klo = Khi + (size_t)HC * phe;
    unsigned short* Vt  = Klo + (size_t)HC * phe;
    proj2_kernel<1><<<dim3(32 * HC), 256, 0, stream>>>(Eh, El, WBh, WBl,
                                                       Qhi, Qlo, Khi, Klo, Vt, h0, HC);
    proj2_kernel<0><<<dim3(32 * 2 * HC), 256, 0, stream>>>(Eh, El, WBh, WBl,
                                                           Qhi, Qlo, Khi, Klo, Vt, h0, HC);
    attn_kernel<<<dim3(32 * HC), 256, 0, stream>>>(Qhi, Qlo, Khi, Klo, Vt, out, h0, HC);
  }
}